// Round 1
// baseline (1984.148 us; speedup 1.0000x reference)
//
#include <hip/hip_runtime.h>

#define DEVI __device__ __forceinline__

typedef __attribute__((ext_vector_type(8))) short bf16x8;
typedef __attribute__((ext_vector_type(4))) float f32x4;
typedef __attribute__((ext_vector_type(4))) unsigned short usx4;

DEVI float bf2f(unsigned short u) {
  unsigned int b = ((unsigned int)u) << 16;
  float f;
  __builtin_memcpy(&f, &b, 4);
  return f;
}
DEVI unsigned short f2bf(float f) {
  unsigned int x;
  __builtin_memcpy(&x, &f, 4);
  x += 0x7FFFu + ((x >> 16) & 1u);
  return (unsigned short)(x >> 16);
}
DEVI void gload_lds16(const void* g, void* l) {
  __builtin_amdgcn_global_load_lds((const __attribute__((address_space(1))) void*)g,
                                   (__attribute__((address_space(3))) void*)l,
                                   16, 0, 0);
}

// ---------------------------------------------------------------------------
// Weight transpose + cast: W[K][N] fp32 -> Wt[N][K] bf16
// ---------------------------------------------------------------------------
__global__ __launch_bounds__(256) void wt_kernel(const float* __restrict__ W,
                                                 unsigned short* __restrict__ Wt,
                                                 int K, int N) {
  __shared__ float t[32][33];
  const int tx = threadIdx.x & 31, ty = threadIdx.x >> 5;  // 32 x 8
  const int n0 = blockIdx.x * 32, k0 = blockIdx.y * 32;
#pragma unroll
  for (int i = 0; i < 4; ++i)
    t[ty * 4 + i][tx] = W[(size_t)(k0 + ty * 4 + i) * N + n0 + tx];
  __syncthreads();
#pragma unroll
  for (int i = 0; i < 4; ++i)
    Wt[(size_t)(n0 + ty * 4 + i) * K + k0 + tx] = f2bf(t[tx][ty * 4 + i]);
}

// ---------------------------------------------------------------------------
// LayerNorm: x fp32 [rows][768] -> bf16 out. One wave per row.
// ---------------------------------------------------------------------------
__global__ __launch_bounds__(256) void ln_kernel(const float* __restrict__ x,
                                                 const float* __restrict__ w,
                                                 const float* __restrict__ b,
                                                 unsigned short* __restrict__ o) {
  const int lane = threadIdx.x & 63;
  const int wave = threadIdx.x >> 6;
  const size_t row = (size_t)blockIdx.x * 4 + wave;
  const float* xr = x + row * 768;
  float v[12];
  float s = 0.f, sq = 0.f;
#pragma unroll
  for (int i = 0; i < 3; ++i) {
    const float4 f = *(const float4*)&xr[i * 256 + lane * 4];
    v[i * 4 + 0] = f.x; v[i * 4 + 1] = f.y; v[i * 4 + 2] = f.z; v[i * 4 + 3] = f.w;
    s += f.x + f.y + f.z + f.w;
    sq += f.x * f.x + f.y * f.y + f.z * f.z + f.w * f.w;
  }
#pragma unroll
  for (int off = 32; off > 0; off >>= 1) {
    s += __shfl_xor(s, off);
    sq += __shfl_xor(sq, off);
  }
  const float mu = s * (1.f / 768.f);
  const float rs = rsqrtf(sq * (1.f / 768.f) - mu * mu + 1e-8f);
  unsigned short* orow = o + row * 768;
#pragma unroll
  for (int i = 0; i < 3; ++i) {
    usx4 st;
#pragma unroll
    for (int j = 0; j < 4; ++j) {
      const int c = i * 256 + lane * 4 + j;
      st[j] = f2bf((v[i * 4 + j] - mu) * rs * w[c] + b[c]);
    }
    *(usx4*)&orow[i * 256 + lane * 4] = st;
  }
}

// ---------------------------------------------------------------------------
// Fused residual + LayerNorm: x2 = x + y (y bf16); write x2 fp32 and LN(x2) bf16
// ---------------------------------------------------------------------------
__global__ __launch_bounds__(256) void fuse_kernel(const float* __restrict__ x,
                                                   const unsigned short* __restrict__ y,
                                                   const float* __restrict__ w,
                                                   const float* __restrict__ b,
                                                   float* __restrict__ x2,
                                                   unsigned short* __restrict__ o) {
  const int lane = threadIdx.x & 63;
  const int wave = threadIdx.x >> 6;
  const size_t row = (size_t)blockIdx.x * 4 + wave;
  const float* xr = x + row * 768;
  const unsigned short* yr = y + row * 768;
  float* x2r = x2 + row * 768;
  float v[12];
  float s = 0.f, sq = 0.f;
#pragma unroll
  for (int i = 0; i < 3; ++i) {
    const float4 f = *(const float4*)&xr[i * 256 + lane * 4];
    const usx4 yv = *(const usx4*)&yr[i * 256 + lane * 4];
    float t0 = f.x + bf2f(yv[0]);
    float t1 = f.y + bf2f(yv[1]);
    float t2 = f.z + bf2f(yv[2]);
    float t3 = f.w + bf2f(yv[3]);
    v[i * 4 + 0] = t0; v[i * 4 + 1] = t1; v[i * 4 + 2] = t2; v[i * 4 + 3] = t3;
    s += t0 + t1 + t2 + t3;
    sq += t0 * t0 + t1 * t1 + t2 * t2 + t3 * t3;
    float4 fo; fo.x = t0; fo.y = t1; fo.z = t2; fo.w = t3;
    *(float4*)&x2r[i * 256 + lane * 4] = fo;
  }
#pragma unroll
  for (int off = 32; off > 0; off >>= 1) {
    s += __shfl_xor(s, off);
    sq += __shfl_xor(sq, off);
  }
  const float mu = s * (1.f / 768.f);
  const float rs = rsqrtf(sq * (1.f / 768.f) - mu * mu + 1e-8f);
  unsigned short* orow = o + row * 768;
#pragma unroll
  for (int i = 0; i < 3; ++i) {
    usx4 st;
#pragma unroll
    for (int j = 0; j < 4; ++j) {
      const int c = i * 256 + lane * 4 + j;
      st[j] = f2bf((v[i * 4 + j] - mu) * rs * w[c] + b[c]);
    }
    *(usx4*)&orow[i * 256 + lane * 4] = st;
  }
}

// ---------------------------------------------------------------------------
// Generic 128x128 bf16 MFMA GEMM: C = A[M,K] @ Bt[N,K]^T + bias, 4 epilogues.
// EPI 0: bf16 store [M,N]. EPI 1: gelu(exact) then bf16 store.
// EPI 2: qkv scatter (O0=q[b,h,s,d] elu+1, O1=kT[b,h,d,s] elu+1, O2=vT[b,h,d,s]).
// EPI 3: OF[r*N+c] += val (fp32 residual RMW).
// ---------------------------------------------------------------------------
template <int EPI>
__global__ __launch_bounds__(256) void gemm_k(const unsigned short* __restrict__ A,
                                              const unsigned short* __restrict__ Bt,
                                              const float* __restrict__ bias, int N, int K,
                                              unsigned short* __restrict__ O0,
                                              unsigned short* __restrict__ O1,
                                              unsigned short* __restrict__ O2,
                                              float* __restrict__ OF) {
  __shared__ unsigned short lA[128 * 32];
  __shared__ unsigned short lB[128 * 32];
  const int tid = threadIdx.x;
  const int lane = tid & 63;
  const int wave = tid >> 6;
  const int wr = wave >> 1, wc = wave & 1;
  const size_t m0 = (size_t)blockIdx.y * 128;
  const size_t n0 = (size_t)blockIdx.x * 128;

  f32x4 acc[4][4];
#pragma unroll
  for (int m = 0; m < 4; ++m)
#pragma unroll
    for (int n = 0; n < 4; ++n) acc[m][n] = f32x4{0.f, 0.f, 0.f, 0.f};

  const size_t rowB = (size_t)K * 2;
  const char* Ab = (const char*)A + m0 * rowB;
  const char* Bb = (const char*)Bt + n0 * rowB;
  char* lAb = (char*)&lA[0];
  char* lBb = (char*)&lB[0];
  const int c0 = tid, c1 = tid + 256;
  const size_t a0 = (size_t)(c0 >> 2) * rowB + (size_t)(c0 & 3) * 16;
  const size_t a1 = (size_t)(c1 >> 2) * rowB + (size_t)(c1 & 3) * 16;
  const int kh = (lane >> 4) * 8;

  const int nk = K >> 5;
  for (int kt = 0; kt < nk; ++kt) {
    const size_t kb = (size_t)kt * 64;
    gload_lds16(Ab + a0 + kb, lAb + wave * 1024);
    gload_lds16(Ab + a1 + kb, lAb + 4096 + wave * 1024);
    gload_lds16(Bb + a0 + kb, lBb + wave * 1024);
    gload_lds16(Bb + a1 + kb, lBb + 4096 + wave * 1024);
    __syncthreads();
    bf16x8 aF[4], bF[4];
#pragma unroll
    for (int m = 0; m < 4; ++m)
      aF[m] = *(const bf16x8*)&lA[(wr * 64 + m * 16 + (lane & 15)) * 32 + kh];
#pragma unroll
    for (int n = 0; n < 4; ++n)
      bF[n] = *(const bf16x8*)&lB[(wc * 64 + n * 16 + (lane & 15)) * 32 + kh];
#pragma unroll
    for (int m = 0; m < 4; ++m)
#pragma unroll
      for (int n = 0; n < 4; ++n)
        acc[m][n] = __builtin_amdgcn_mfma_f32_16x16x32_bf16(aF[m], bF[n], acc[m][n], 0, 0, 0);
    __syncthreads();
  }

  const int rl = (lane >> 4) * 4;
  const int cl = lane & 15;
#pragma unroll
  for (int m = 0; m < 4; ++m) {
    const size_t r0 = m0 + wr * 64 + m * 16 + rl;
#pragma unroll
    for (int n = 0; n < 4; ++n) {
      const size_t c = n0 + wc * 64 + n * 16 + cl;
      const float bv = bias[c];
      if (EPI == 0) {
#pragma unroll
        for (int j = 0; j < 4; ++j) O0[(r0 + j) * (size_t)N + c] = f2bf(acc[m][n][j] + bv);
      } else if (EPI == 1) {
#pragma unroll
        for (int j = 0; j < 4; ++j) {
          float v = acc[m][n][j] + bv;
          v = 0.5f * v * (1.0f + erff(v * 0.70710678118654752f));
          O0[(r0 + j) * (size_t)N + c] = f2bf(v);
        }
      } else if (EPI == 2) {
        const int t = (int)(c / 768);
        const int rem = (int)c - t * 768;
        const int h = rem >> 6, d = rem & 63;
        const int b = (int)(r0 >> 12);
        const int s = (int)(r0 & 4095);
        const size_t bh = (size_t)b * 12 + h;
        if (t == 0) {
#pragma unroll
          for (int j = 0; j < 4; ++j) {
            float v = acc[m][n][j] + bv;
            v = v > 0.f ? v + 1.f : __expf(v);
            O0[(bh * 4096 + (size_t)(s + j)) * 64 + d] = f2bf(v);
          }
        } else {
          usx4 st;
#pragma unroll
          for (int j = 0; j < 4; ++j) {
            float v = acc[m][n][j] + bv;
            if (t == 1) v = v > 0.f ? v + 1.f : __expf(v);
            st[j] = f2bf(v);
          }
          unsigned short* dst = (t == 1) ? O1 : O2;
          *(usx4*)&dst[(bh * 64 + d) * 4096 + s] = st;
        }
      } else {  // EPI == 3: residual RMW into fp32 out
#pragma unroll
        for (int j = 0; j < 4; ++j) {
          const size_t idx = (r0 + j) * (size_t)N + c;
          OF[idx] += acc[m][n][j] + bv;
        }
      }
    }
  }
}

// ---------------------------------------------------------------------------
// kv[d][e] = sum_s k[s,d] v[s,e] per (b,h). kT/vT are [bh][64][4096] bf16.
// Writes kvT[bh][e][d] fp32. 4 waves split s-range; LDS reduce.
// ---------------------------------------------------------------------------
__global__ __launch_bounds__(256) void kv_kernel(const unsigned short* __restrict__ kT,
                                                 const unsigned short* __restrict__ vT,
                                                 float* __restrict__ kvT) {
  __shared__ float red[4 * 64 * 64];  // 64 KB
  const int tid = threadIdx.x;
  const int lane = tid & 63, wave = tid >> 6;
  const size_t bh = blockIdx.x;
  const unsigned short* kb = kT + bh * (size_t)(64 * 4096);
  const unsigned short* vb = vT + bh * (size_t)(64 * 4096);
  f32x4 acc[4][4];
#pragma unroll
  for (int m = 0; m < 4; ++m)
#pragma unroll
    for (int n = 0; n < 4; ++n) acc[m][n] = f32x4{0.f, 0.f, 0.f, 0.f};
  const int kh = (lane >> 4) * 8;
  for (int st = 0; st < 32; ++st) {
    const int s0 = wave * 1024 + st * 32 + kh;
    bf16x8 aF[4], bF[4];
#pragma unroll
    for (int m = 0; m < 4; ++m)
      aF[m] = *(const bf16x8*)&kb[(size_t)((lane & 15) + 16 * m) * 4096 + s0];
#pragma unroll
    for (int n = 0; n < 4; ++n)
      bF[n] = *(const bf16x8*)&vb[(size_t)((lane & 15) + 16 * n) * 4096 + s0];
#pragma unroll
    for (int m = 0; m < 4; ++m)
#pragma unroll
      for (int n = 0; n < 4; ++n)
        acc[m][n] = __builtin_amdgcn_mfma_f32_16x16x32_bf16(aF[m], bF[n], acc[m][n], 0, 0, 0);
  }
#pragma unroll
  for (int m = 0; m < 4; ++m)
#pragma unroll
    for (int n = 0; n < 4; ++n)
#pragma unroll
      for (int j = 0; j < 4; ++j)
        red[wave * 4096 + (m * 16 + (lane >> 4) * 4 + j) * 64 + n * 16 + (lane & 15)] =
            acc[m][n][j];
  __syncthreads();
  for (int i = 0; i < 16; ++i) {
    const int f = i * 256 + tid;
    float s = 0.f;
#pragma unroll
    for (int w = 0; w < 4; ++w) s += red[w * 4096 + f];
    const int d = f >> 6, e = f & 63;
    kvT[bh * 4096 + e * 64 + d] = s;  // transposed store
  }
}

// ---------------------------------------------------------------------------
// ksum[bh][d] = sum_s kT[bh][d][s]
// ---------------------------------------------------------------------------
__global__ __launch_bounds__(256) void ksum_kernel(const unsigned short* __restrict__ kT,
                                                   float* __restrict__ ksum) {
  __shared__ float part[256];
  const int tid = threadIdx.x;
  const int d = tid & 63, p = tid >> 6;
  const size_t bh = blockIdx.x;
  const unsigned short* kb = kT + bh * (size_t)(64 * 4096) + (size_t)d * 4096 + p * 1024;
  float s = 0.f;
  for (int i = 0; i < 128; ++i) {
    const bf16x8 v = *(const bf16x8*)&kb[i * 8];
#pragma unroll
    for (int j = 0; j < 8; ++j) s += bf2f((unsigned short)v[j]);
  }
  part[tid] = s;
  __syncthreads();
  if (tid < 64) ksum[bh * 64 + d] = part[d] + part[64 + d] + part[128 + d] + part[192 + d];
}

// ---------------------------------------------------------------------------
// attn out: out[s,e] = z_s * sum_d q[s,d] kv[d,e]; z_s = 1/sum_d q[s,d] ksum[d]
// q[bh][s][d] bf16; kvT[bh][e][d] fp32; writes attnout[b][s][h*64+e] bf16.
// Block = (bh, s-chunk of 1024); 4 waves x 4 subtiles of 64 s.
// ---------------------------------------------------------------------------
__global__ __launch_bounds__(256) void attn_out_kernel(const unsigned short* __restrict__ q,
                                                       const float* __restrict__ kvT,
                                                       const float* __restrict__ ksum,
                                                       unsigned short* __restrict__ attnout) {
  __shared__ float kvl[4096];
  __shared__ float ksl[64];
  __shared__ float zl[4 * 64];
  const int tid = threadIdx.x;
  const int lane = tid & 63, wave = tid >> 6;
  const int bh = blockIdx.x >> 2;
  const int chunk = blockIdx.x & 3;
  const int b = bh / 12, h = bh % 12;
  const float* kvb = kvT + (size_t)bh * 4096;
  for (int i = tid; i < 4096; i += 256) kvl[i] = kvb[i];
  if (tid < 64) ksl[tid] = ksum[(size_t)bh * 64 + tid];
  __syncthreads();

  const int kh = (lane >> 4) * 8;
  bf16x8 bF[4], ksF;
#pragma unroll
  for (int n = 0; n < 4; ++n) {
    bf16x8 t;
#pragma unroll
    for (int j = 0; j < 8; ++j)
      t[j] = (short)f2bf(kvl[((lane & 15) + 16 * n) * 64 + kh + j]);
    bF[n] = t;
  }
  {
    bf16x8 t;
#pragma unroll
    for (int j = 0; j < 8; ++j)
      t[j] = ((lane & 15) == 0) ? (short)f2bf(ksl[kh + j]) : (short)0;
    ksF = t;
  }
  const unsigned short* qb = q + (size_t)bh * 4096 * 64;

  for (int st = 0; st < 4; ++st) {
    const int s0 = chunk * 1024 + wave * 256 + st * 64;
    bf16x8 aF[4];
#pragma unroll
    for (int m = 0; m < 4; ++m)
      aF[m] = *(const bf16x8*)&qb[(size_t)(s0 + (lane & 15) + 16 * m) * 64 + kh];
    f32x4 acc[4][4];
    f32x4 dacc[4];
#pragma unroll
    for (int m = 0; m < 4; ++m) {
      dacc[m] = f32x4{0.f, 0.f, 0.f, 0.f};
#pragma unroll
      for (int n = 0; n < 4; ++n) acc[m][n] = f32x4{0.f, 0.f, 0.f, 0.f};
    }
#pragma unroll
    for (int m = 0; m < 4; ++m) {
#pragma unroll
      for (int n = 0; n < 4; ++n)
        acc[m][n] = __builtin_amdgcn_mfma_f32_16x16x32_bf16(aF[m], bF[n], acc[m][n], 0, 0, 0);
      dacc[m] = __builtin_amdgcn_mfma_f32_16x16x32_bf16(aF[m], ksF, dacc[m], 0, 0, 0);
    }
    if ((lane & 15) == 0) {
#pragma unroll
      for (int m = 0; m < 4; ++m)
#pragma unroll
        for (int j = 0; j < 4; ++j)
          zl[wave * 64 + m * 16 + (lane >> 4) * 4 + j] = 1.0f / dacc[m][j];
    }
    __syncthreads();
#pragma unroll
    for (int m = 0; m < 4; ++m)
#pragma unroll
      for (int n = 0; n < 4; ++n)
#pragma unroll
        for (int j = 0; j < 4; ++j) {
          const int sl = m * 16 + (lane >> 4) * 4 + j;
          const int s = s0 + sl;
          const float v = acc[m][n][j] * zl[wave * 64 + sl];
          const int e = n * 16 + (lane & 15);
          attnout[((size_t)b * 4096 + s) * 768 + h * 64 + e] = f2bf(v);
        }
    __syncthreads();
  }
}

// ---------------------------------------------------------------------------
extern "C" void kernel_launch(void* const* d_in, const int* in_sizes, int n_in,
                              void* d_out, int out_size, void* d_ws, size_t ws_size,
                              hipStream_t stream) {
  const float* x = (const float*)d_in[0];
  const float* qkv_w = (const float*)d_in[1];
  const float* qkv_b = (const float*)d_in[2];
  const float* proj_w = (const float*)d_in[3];
  const float* proj_b = (const float*)d_in[4];
  const float* fc1_w = (const float*)d_in[5];
  const float* fc1_b = (const float*)d_in[6];
  const float* fc2_w = (const float*)d_in[7];
  const float* fc2_b = (const float*)d_in[8];
  const float* ln1_w = (const float*)d_in[9];
  const float* ln1_b = (const float*)d_in[10];
  const float* ln2_w = (const float*)d_in[11];
  const float* ln2_b = (const float*)d_in[12];
  float* out = (float*)d_out;

  char* ws = (char*)d_ws;
  const size_t PL = (size_t)65536 * 768 * 2;  // 100,663,296 bytes (one bf16 plane)
  unsigned short* xn = (unsigned short*)(ws + 0 * PL);       // plane 0
  unsigned short* q = (unsigned short*)(ws + 1 * PL);        // plane 1
  unsigned short* kT = (unsigned short*)(ws + 2 * PL);       // plane 2
  unsigned short* vT = (unsigned short*)(ws + 3 * PL);       // plane 3
  unsigned short* attnout = xn;                               // reuse plane 0
  unsigned short* ybuf = kT;                                  // reuse plane 2
  unsigned short* xn2 = (unsigned short*)(ws + 4 * PL);      // plane 4
  unsigned short* hbuf = (unsigned short*)(ws + 0 * PL);     // planes 0-3 (403 MB)
  size_t off = 5 * PL;
  float* kvT = (float*)(ws + off); off += (size_t)192 * 4096 * 4;
  float* ksum = (float*)(ws + off); off += (size_t)192 * 64 * 4;
  unsigned short* qkvWt = (unsigned short*)(ws + off); off += (size_t)2304 * 768 * 2;
  unsigned short* projWt = (unsigned short*)(ws + off); off += (size_t)768 * 768 * 2;
  unsigned short* fc1Wt = (unsigned short*)(ws + off); off += (size_t)3072 * 768 * 2;
  unsigned short* fc2Wt = (unsigned short*)(ws + off); off += (size_t)768 * 3072 * 2;

  // 1. weight transpose+cast
  wt_kernel<<<dim3(72, 24), 256, 0, stream>>>(qkv_w, qkvWt, 768, 2304);
  wt_kernel<<<dim3(24, 24), 256, 0, stream>>>(proj_w, projWt, 768, 768);
  wt_kernel<<<dim3(96, 24), 256, 0, stream>>>(fc1_w, fc1Wt, 768, 3072);
  wt_kernel<<<dim3(24, 96), 256, 0, stream>>>(fc2_w, fc2Wt, 3072, 768);
  // 2. LN1
  ln_kernel<<<16384, 256, 0, stream>>>(x, ln1_w, ln1_b, xn);
  // 3. qkv GEMM with elu+1 + transposed k/v scatter
  gemm_k<2><<<dim3(18, 512), 256, 0, stream>>>(xn, qkvWt, qkv_b, 2304, 768, q, kT, vT, nullptr);
  // 4. ksum
  ksum_kernel<<<192, 256, 0, stream>>>(kT, ksum);
  // 5. kv
  kv_kernel<<<192, 256, 0, stream>>>(kT, vT, kvT);
  // 6. attention out
  attn_out_kernel<<<768, 256, 0, stream>>>(q, kvT, ksum, attnout);
  // 7. proj GEMM -> y
  gemm_k<0><<<dim3(6, 512), 256, 0, stream>>>(attnout, projWt, proj_b, 768, 768, ybuf, nullptr,
                                              nullptr, nullptr);
  // 8. residual + LN2 (x2 lives in d_out)
  fuse_kernel<<<16384, 256, 0, stream>>>(x, ybuf, ln2_w, ln2_b, out, xn2);
  // 9. fc1 + gelu
  gemm_k<1><<<dim3(24, 512), 256, 0, stream>>>(xn2, fc1Wt, fc1_b, 3072, 768, hbuf, nullptr,
                                               nullptr, nullptr);
  // 10. fc2 + residual RMW into out
  gemm_k<3><<<dim3(6, 512), 256, 0, stream>>>(hbuf, fc2Wt, fc2_b, 768, 3072, nullptr, nullptr,
                                              nullptr, out);
  (void)in_sizes; (void)n_in; (void)out_size; (void)ws_size;
}

// Round 2
// 1734.005 us; speedup vs baseline: 1.1443x; 1.1443x over previous
//
#include <hip/hip_runtime.h>

#define DEVI __device__ __forceinline__

typedef __attribute__((ext_vector_type(8))) short bf16x8;
typedef __attribute__((ext_vector_type(4))) float f32x4;
typedef __attribute__((ext_vector_type(4))) unsigned short usx4;

DEVI float bf2f(unsigned short u) {
  unsigned int b = ((unsigned int)u) << 16;
  float f;
  __builtin_memcpy(&f, &b, 4);
  return f;
}
DEVI unsigned short f2bf(float f) {
  unsigned int x;
  __builtin_memcpy(&x, &f, 4);
  x += 0x7FFFu + ((x >> 16) & 1u);
  return (unsigned short)(x >> 16);
}
DEVI void gload_lds16(const void* g, void* l) {
  __builtin_amdgcn_global_load_lds((const __attribute__((address_space(1))) void*)g,
                                   (__attribute__((address_space(3))) void*)l,
                                   16, 0, 0);
}

// ---------------------------------------------------------------------------
// Weight transpose + cast: W[K][N] fp32 -> Wt[N][K] bf16
// ---------------------------------------------------------------------------
__global__ __launch_bounds__(256) void wt_kernel(const float* __restrict__ W,
                                                 unsigned short* __restrict__ Wt,
                                                 int K, int N) {
  __shared__ float t[32][33];
  const int tx = threadIdx.x & 31, ty = threadIdx.x >> 5;  // 32 x 8
  const int n0 = blockIdx.x * 32, k0 = blockIdx.y * 32;
#pragma unroll
  for (int i = 0; i < 4; ++i)
    t[ty * 4 + i][tx] = W[(size_t)(k0 + ty * 4 + i) * N + n0 + tx];
  __syncthreads();
#pragma unroll
  for (int i = 0; i < 4; ++i)
    Wt[(size_t)(n0 + ty * 4 + i) * K + k0 + tx] = f2bf(t[tx][ty * 4 + i]);
}

// ---------------------------------------------------------------------------
// LayerNorm: x fp32 [rows][768] -> bf16 out. One wave per row.
// ---------------------------------------------------------------------------
__global__ __launch_bounds__(256) void ln_kernel(const float* __restrict__ x,
                                                 const float* __restrict__ w,
                                                 const float* __restrict__ b,
                                                 unsigned short* __restrict__ o) {
  const int lane = threadIdx.x & 63;
  const int wave = threadIdx.x >> 6;
  const size_t row = (size_t)blockIdx.x * 4 + wave;
  const float* xr = x + row * 768;
  float v[12];
  float s = 0.f, sq = 0.f;
#pragma unroll
  for (int i = 0; i < 3; ++i) {
    const float4 f = *(const float4*)&xr[i * 256 + lane * 4];
    v[i * 4 + 0] = f.x; v[i * 4 + 1] = f.y; v[i * 4 + 2] = f.z; v[i * 4 + 3] = f.w;
    s += f.x + f.y + f.z + f.w;
    sq += f.x * f.x + f.y * f.y + f.z * f.z + f.w * f.w;
  }
#pragma unroll
  for (int off = 32; off > 0; off >>= 1) {
    s += __shfl_xor(s, off);
    sq += __shfl_xor(sq, off);
  }
  const float mu = s * (1.f / 768.f);
  const float rs = rsqrtf(sq * (1.f / 768.f) - mu * mu + 1e-8f);
  unsigned short* orow = o + row * 768;
#pragma unroll
  for (int i = 0; i < 3; ++i) {
    usx4 st;
#pragma unroll
    for (int j = 0; j < 4; ++j) {
      const int c = i * 256 + lane * 4 + j;
      st[j] = f2bf((v[i * 4 + j] - mu) * rs * w[c] + b[c]);
    }
    *(usx4*)&orow[i * 256 + lane * 4] = st;
  }
}

// ---------------------------------------------------------------------------
// Fused residual + LayerNorm: x2 = x + y (y bf16); write x2 fp32 and LN(x2) bf16
// ---------------------------------------------------------------------------
__global__ __launch_bounds__(256) void fuse_kernel(const float* __restrict__ x,
                                                   const unsigned short* __restrict__ y,
                                                   const float* __restrict__ w,
                                                   const float* __restrict__ b,
                                                   float* __restrict__ x2,
                                                   unsigned short* __restrict__ o) {
  const int lane = threadIdx.x & 63;
  const int wave = threadIdx.x >> 6;
  const size_t row = (size_t)blockIdx.x * 4 + wave;
  const float* xr = x + row * 768;
  const unsigned short* yr = y + row * 768;
  float* x2r = x2 + row * 768;
  float v[12];
  float s = 0.f, sq = 0.f;
#pragma unroll
  for (int i = 0; i < 3; ++i) {
    const float4 f = *(const float4*)&xr[i * 256 + lane * 4];
    const usx4 yv = *(const usx4*)&yr[i * 256 + lane * 4];
    float t0 = f.x + bf2f(yv[0]);
    float t1 = f.y + bf2f(yv[1]);
    float t2 = f.z + bf2f(yv[2]);
    float t3 = f.w + bf2f(yv[3]);
    v[i * 4 + 0] = t0; v[i * 4 + 1] = t1; v[i * 4 + 2] = t2; v[i * 4 + 3] = t3;
    s += t0 + t1 + t2 + t3;
    sq += t0 * t0 + t1 * t1 + t2 * t2 + t3 * t3;
    float4 fo; fo.x = t0; fo.y = t1; fo.z = t2; fo.w = t3;
    *(float4*)&x2r[i * 256 + lane * 4] = fo;
  }
#pragma unroll
  for (int off = 32; off > 0; off >>= 1) {
    s += __shfl_xor(s, off);
    sq += __shfl_xor(sq, off);
  }
  const float mu = s * (1.f / 768.f);
  const float rs = rsqrtf(sq * (1.f / 768.f) - mu * mu + 1e-8f);
  unsigned short* orow = o + row * 768;
#pragma unroll
  for (int i = 0; i < 3; ++i) {
    usx4 st;
#pragma unroll
    for (int j = 0; j < 4; ++j) {
      const int c = i * 256 + lane * 4 + j;
      st[j] = f2bf((v[i * 4 + j] - mu) * rs * w[c] + b[c]);
    }
    *(usx4*)&orow[i * 256 + lane * 4] = st;
  }
}

// ---------------------------------------------------------------------------
// 256x256 bf16 MFMA GEMM engine. BK=32, 512 threads (8 waves, 2Mx4N),
// 4-buffer LDS ring (128KB), counted vmcnt(8), one raw s_barrier per K-tile,
// XOR chunk swizzle (paired 128B rows) staged via pre-swizzled global source.
// C = A[M,K] @ Bt[N,K]^T + bias. Epilogues as in gemm_k.
// ---------------------------------------------------------------------------
template <int EPI>
__global__ __launch_bounds__(512, 2) void gemm256_k(
    const unsigned short* __restrict__ A, const unsigned short* __restrict__ Bt,
    const float* __restrict__ bias, int N, int K,
    unsigned short* __restrict__ O0, unsigned short* __restrict__ O1,
    unsigned short* __restrict__ O2, float* __restrict__ OF) {
  __shared__ char lds[131072];
  const int tid = threadIdx.x;
  const int lane = tid & 63, wave = tid >> 6;
  const int wr = wave >> 2, wc = wave & 3;

  // T1: XCD-chunked block swizzle (nwg % 8 == 0 for all our grids)
  const int gx = gridDim.x;
  const int nwg = gx * gridDim.y;
  const int cpx = nwg >> 3;
  const int wgid = blockIdx.x + gx * blockIdx.y;
  const int v = (wgid & 7) * cpx + (wgid >> 3);
  const size_t n0 = (size_t)(v % gx) * 256;
  const size_t m0 = (size_t)(v / gx) * 256;

  const size_t ldg = (size_t)K * 2;  // row stride bytes for A and Bt
  const char* Abase = (const char*)A + m0 * ldg;
  const char* Bbase = (const char*)Bt + n0 * ldg;

  // staging: phys chunk q in [0,1024) holds logical (row = rp*2 + (lc>>2),
  // kchunk = lc&3) with rp=q>>3, lc=(q&7)^(rp&7). Source pre-swizzled.
  const int q0 = tid, q1 = tid + 512;
  const int rp0 = q0 >> 3, rp1 = q1 >> 3;
  const int lc0 = (q0 & 7) ^ (rp0 & 7), lc1 = (q1 & 7) ^ (rp1 & 7);
  const size_t go0 = (size_t)(rp0 * 2 + (lc0 >> 2)) * ldg + (size_t)(lc0 & 3) * 16;
  const size_t go1 = (size_t)(rp1 * 2 + (lc1 >> 2)) * ldg + (size_t)(lc1 & 3) * 16;
  const char* aS0 = Abase + go0;
  const char* aS1 = Abase + go1;
  const char* bS0 = Bbase + go0;
  const char* bS1 = Bbase + go1;
  char* ldsb = (char*)lds;
  const int d0 = tid * 16, d1 = 8192 + tid * 16;

  f32x4 acc[8][4];
#pragma unroll
  for (int m = 0; m < 8; ++m)
#pragma unroll
    for (int n = 0; n < 4; ++n) acc[m][n] = f32x4{0.f, 0.f, 0.f, 0.f};

  // fragment-read addressing (swizzled)
  const int L = lane & 15, kc4 = lane >> 4;
  const int pcv = (((L & 1) << 2) | kc4) ^ (L >> 1);
  const int aro = wr * 8192 + (L >> 1) * 128 + pcv * 16;
  const int bro = 16384 + wc * 4096 + (L >> 1) * 128 + pcv * 16;

  const int nt = K >> 5;

#define STAGE(tt)                                              \
  do {                                                         \
    char* dst_ = ldsb + ((tt) & 3) * 32768;                    \
    const size_t ko_ = (size_t)(tt) * 64;                      \
    gload_lds16(aS0 + ko_, dst_ + d0);                         \
    gload_lds16(aS1 + ko_, dst_ + d1);                         \
    gload_lds16(bS0 + ko_, dst_ + 16384 + d0);                 \
    gload_lds16(bS1 + ko_, dst_ + 16384 + d1);                 \
  } while (0)

  STAGE(0);
  STAGE(1);
  STAGE(2);

  for (int t = 0; t < nt; ++t) {
    const int rem = nt - t;
    if (rem > 2)
      asm volatile("s_waitcnt vmcnt(8) lgkmcnt(0)" ::: "memory");
    else if (rem == 2)
      asm volatile("s_waitcnt vmcnt(4) lgkmcnt(0)" ::: "memory");
    else
      asm volatile("s_waitcnt vmcnt(0) lgkmcnt(0)" ::: "memory");
    __builtin_amdgcn_s_barrier();
    asm volatile("" ::: "memory");
    if (t + 3 < nt) STAGE(t + 3);
    const char* base = ldsb + (t & 3) * 32768;
    bf16x8 bF[4];
#pragma unroll
    for (int n = 0; n < 4; ++n) bF[n] = *(const bf16x8*)(base + bro + n * 1024);
    // phase 0: m-frags 0..3
    {
      bf16x8 aF[4];
#pragma unroll
      for (int m = 0; m < 4; ++m) aF[m] = *(const bf16x8*)(base + aro + m * 1024);
      __builtin_amdgcn_s_setprio(1);
#pragma unroll
      for (int m = 0; m < 4; ++m)
#pragma unroll
        for (int n = 0; n < 4; ++n)
          acc[m][n] = __builtin_amdgcn_mfma_f32_16x16x32_bf16(aF[m], bF[n], acc[m][n], 0, 0, 0);
      __builtin_amdgcn_s_setprio(0);
    }
    // phase 1: m-frags 4..7
    {
      bf16x8 aF[4];
#pragma unroll
      for (int m = 0; m < 4; ++m) aF[m] = *(const bf16x8*)(base + aro + (m + 4) * 1024);
      __builtin_amdgcn_s_setprio(1);
#pragma unroll
      for (int m = 0; m < 4; ++m)
#pragma unroll
        for (int n = 0; n < 4; ++n)
          acc[m + 4][n] = __builtin_amdgcn_mfma_f32_16x16x32_bf16(aF[m], bF[n], acc[m + 4][n], 0, 0, 0);
      __builtin_amdgcn_s_setprio(0);
    }
  }
#undef STAGE

  // epilogue
  const int rl = (lane >> 4) * 4;
  const int cl = lane & 15;
#pragma unroll
  for (int m = 0; m < 8; ++m) {
    const size_t r0 = m0 + wr * 128 + m * 16 + rl;
#pragma unroll
    for (int n = 0; n < 4; ++n) {
      const size_t c = n0 + wc * 64 + n * 16 + cl;
      const float bv = bias[c];
      if (EPI == 0) {
#pragma unroll
        for (int j = 0; j < 4; ++j) O0[(r0 + j) * (size_t)N + c] = f2bf(acc[m][n][j] + bv);
      } else if (EPI == 1) {
#pragma unroll
        for (int j = 0; j < 4; ++j) {
          float val = acc[m][n][j] + bv;
          val = 0.5f * val * (1.0f + erff(val * 0.70710678118654752f));
          O0[(r0 + j) * (size_t)N + c] = f2bf(val);
        }
      } else if (EPI == 2) {
        const int t = (int)(c / 768);
        const int rem = (int)c - t * 768;
        const int h = rem >> 6, d = rem & 63;
        const int b = (int)(r0 >> 12);
        const int s = (int)(r0 & 4095);
        const size_t bh = (size_t)b * 12 + h;
        if (t == 0) {
#pragma unroll
          for (int j = 0; j < 4; ++j) {
            float val = acc[m][n][j] + bv;
            val = val > 0.f ? val + 1.f : __expf(val);
            O0[(bh * 4096 + (size_t)(s + j)) * 64 + d] = f2bf(val);
          }
        } else {
          usx4 st;
#pragma unroll
          for (int j = 0; j < 4; ++j) {
            float val = acc[m][n][j] + bv;
            if (t == 1) val = val > 0.f ? val + 1.f : __expf(val);
            st[j] = f2bf(val);
          }
          unsigned short* dst = (t == 1) ? O1 : O2;
          *(usx4*)&dst[(bh * 64 + d) * 4096 + s] = st;
        }
      } else {  // EPI == 3: residual RMW into fp32 out
#pragma unroll
        for (int j = 0; j < 4; ++j) {
          const size_t idx = (r0 + j) * (size_t)N + c;
          OF[idx] += acc[m][n][j] + bv;
        }
      }
    }
  }
}

// ---------------------------------------------------------------------------
// kv[d][e] = sum_s k[s,d] v[s,e] per (b,h). kT/vT are [bh][64][4096] bf16.
// Writes kvT[bh][e][d] fp32. 4 waves split s-range; LDS reduce.
// ---------------------------------------------------------------------------
__global__ __launch_bounds__(256) void kv_kernel(const unsigned short* __restrict__ kT,
                                                 const unsigned short* __restrict__ vT,
                                                 float* __restrict__ kvT) {
  __shared__ float red[4 * 64 * 64];  // 64 KB
  const int tid = threadIdx.x;
  const int lane = tid & 63, wave = tid >> 6;
  const size_t bh = blockIdx.x;
  const unsigned short* kb = kT + bh * (size_t)(64 * 4096);
  const unsigned short* vb = vT + bh * (size_t)(64 * 4096);
  f32x4 acc[4][4];
#pragma unroll
  for (int m = 0; m < 4; ++m)
#pragma unroll
    for (int n = 0; n < 4; ++n) acc[m][n] = f32x4{0.f, 0.f, 0.f, 0.f};
  const int kh = (lane >> 4) * 8;
  for (int st = 0; st < 32; ++st) {
    const int s0 = wave * 1024 + st * 32 + kh;
    bf16x8 aF[4], bF[4];
#pragma unroll
    for (int m = 0; m < 4; ++m)
      aF[m] = *(const bf16x8*)&kb[(size_t)((lane & 15) + 16 * m) * 4096 + s0];
#pragma unroll
    for (int n = 0; n < 4; ++n)
      bF[n] = *(const bf16x8*)&vb[(size_t)((lane & 15) + 16 * n) * 4096 + s0];
#pragma unroll
    for (int m = 0; m < 4; ++m)
#pragma unroll
      for (int n = 0; n < 4; ++n)
        acc[m][n] = __builtin_amdgcn_mfma_f32_16x16x32_bf16(aF[m], bF[n], acc[m][n], 0, 0, 0);
  }
#pragma unroll
  for (int m = 0; m < 4; ++m)
#pragma unroll
    for (int n = 0; n < 4; ++n)
#pragma unroll
      for (int j = 0; j < 4; ++j)
        red[wave * 4096 + (m * 16 + (lane >> 4) * 4 + j) * 64 + n * 16 + (lane & 15)] =
            acc[m][n][j];
  __syncthreads();
  for (int i = 0; i < 16; ++i) {
    const int f = i * 256 + tid;
    float s = 0.f;
#pragma unroll
    for (int w = 0; w < 4; ++w) s += red[w * 4096 + f];
    const int d = f >> 6, e = f & 63;
    kvT[bh * 4096 + e * 64 + d] = s;  // transposed store
  }
}

// ---------------------------------------------------------------------------
// ksum[bh][d] = sum_s kT[bh][d][s]
// ---------------------------------------------------------------------------
__global__ __launch_bounds__(256) void ksum_kernel(const unsigned short* __restrict__ kT,
                                                   float* __restrict__ ksum) {
  __shared__ float part[256];
  const int tid = threadIdx.x;
  const int d = tid & 63, p = tid >> 6;
  const size_t bh = blockIdx.x;
  const unsigned short* kb = kT + bh * (size_t)(64 * 4096) + (size_t)d * 4096 + p * 1024;
  float s = 0.f;
  for (int i = 0; i < 128; ++i) {
    const bf16x8 v = *(const bf16x8*)&kb[i * 8];
#pragma unroll
    for (int j = 0; j < 8; ++j) s += bf2f((unsigned short)v[j]);
  }
  part[tid] = s;
  __syncthreads();
  if (tid < 64) ksum[bh * 64 + d] = part[d] + part[64 + d] + part[128 + d] + part[192 + d];
}

// ---------------------------------------------------------------------------
// attn out: out[s,e] = z_s * sum_d q[s,d] kv[d,e]; z_s = 1/sum_d q[s,d] ksum[d]
// ---------------------------------------------------------------------------
__global__ __launch_bounds__(256) void attn_out_kernel(const unsigned short* __restrict__ q,
                                                       const float* __restrict__ kvT,
                                                       const float* __restrict__ ksum,
                                                       unsigned short* __restrict__ attnout) {
  __shared__ float kvl[4096];
  __shared__ float ksl[64];
  __shared__ float zl[4 * 64];
  const int tid = threadIdx.x;
  const int lane = tid & 63, wave = tid >> 6;
  const int bh = blockIdx.x >> 2;
  const int chunk = blockIdx.x & 3;
  const int b = bh / 12, h = bh % 12;
  const float* kvb = kvT + (size_t)bh * 4096;
  for (int i = tid; i < 4096; i += 256) kvl[i] = kvb[i];
  if (tid < 64) ksl[tid] = ksum[(size_t)bh * 64 + tid];
  __syncthreads();

  const int kh = (lane >> 4) * 8;
  bf16x8 bF[4], ksF;
#pragma unroll
  for (int n = 0; n < 4; ++n) {
    bf16x8 t;
#pragma unroll
    for (int j = 0; j < 8; ++j)
      t[j] = (short)f2bf(kvl[((lane & 15) + 16 * n) * 64 + kh + j]);
    bF[n] = t;
  }
  {
    bf16x8 t;
#pragma unroll
    for (int j = 0; j < 8; ++j)
      t[j] = ((lane & 15) == 0) ? (short)f2bf(ksl[kh + j]) : (short)0;
    ksF = t;
  }
  const unsigned short* qb = q + (size_t)bh * 4096 * 64;

  for (int st = 0; st < 4; ++st) {
    const int s0 = chunk * 1024 + wave * 256 + st * 64;
    bf16x8 aF[4];
#pragma unroll
    for (int m = 0; m < 4; ++m)
      aF[m] = *(const bf16x8*)&qb[(size_t)(s0 + (lane & 15) + 16 * m) * 64 + kh];
    f32x4 acc[4][4];
    f32x4 dacc[4];
#pragma unroll
    for (int m = 0; m < 4; ++m) {
      dacc[m] = f32x4{0.f, 0.f, 0.f, 0.f};
#pragma unroll
      for (int n = 0; n < 4; ++n) acc[m][n] = f32x4{0.f, 0.f, 0.f, 0.f};
    }
#pragma unroll
    for (int m = 0; m < 4; ++m) {
#pragma unroll
      for (int n = 0; n < 4; ++n)
        acc[m][n] = __builtin_amdgcn_mfma_f32_16x16x32_bf16(aF[m], bF[n], acc[m][n], 0, 0, 0);
      dacc[m] = __builtin_amdgcn_mfma_f32_16x16x32_bf16(aF[m], ksF, dacc[m], 0, 0, 0);
    }
    if ((lane & 15) == 0) {
#pragma unroll
      for (int m = 0; m < 4; ++m)
#pragma unroll
        for (int j = 0; j < 4; ++j)
          zl[wave * 64 + m * 16 + (lane >> 4) * 4 + j] = 1.0f / dacc[m][j];
    }
    __syncthreads();
#pragma unroll
    for (int m = 0; m < 4; ++m)
#pragma unroll
      for (int n = 0; n < 4; ++n)
#pragma unroll
        for (int j = 0; j < 4; ++j) {
          const int sl = m * 16 + (lane >> 4) * 4 + j;
          const int s = s0 + sl;
          const float val = acc[m][n][j] * zl[wave * 64 + sl];
          const int e = n * 16 + (lane & 15);
          attnout[((size_t)b * 4096 + s) * 768 + h * 64 + e] = f2bf(val);
        }
    __syncthreads();
  }
}

// ---------------------------------------------------------------------------
extern "C" void kernel_launch(void* const* d_in, const int* in_sizes, int n_in,
                              void* d_out, int out_size, void* d_ws, size_t ws_size,
                              hipStream_t stream) {
  const float* x = (const float*)d_in[0];
  const float* qkv_w = (const float*)d_in[1];
  const float* qkv_b = (const float*)d_in[2];
  const float* proj_w = (const float*)d_in[3];
  const float* proj_b = (const float*)d_in[4];
  const float* fc1_w = (const float*)d_in[5];
  const float* fc1_b = (const float*)d_in[6];
  const float* fc2_w = (const float*)d_in[7];
  const float* fc2_b = (const float*)d_in[8];
  const float* ln1_w = (const float*)d_in[9];
  const float* ln1_b = (const float*)d_in[10];
  const float* ln2_w = (const float*)d_in[11];
  const float* ln2_b = (const float*)d_in[12];
  float* out = (float*)d_out;

  char* ws = (char*)d_ws;
  const size_t PL = (size_t)65536 * 768 * 2;  // one bf16 plane
  unsigned short* xn = (unsigned short*)(ws + 0 * PL);
  unsigned short* q = (unsigned short*)(ws + 1 * PL);
  unsigned short* kT = (unsigned short*)(ws + 2 * PL);
  unsigned short* vT = (unsigned short*)(ws + 3 * PL);
  unsigned short* attnout = xn;
  unsigned short* ybuf = kT;
  unsigned short* xn2 = (unsigned short*)(ws + 4 * PL);
  unsigned short* hbuf = (unsigned short*)(ws + 0 * PL);  // planes 0-3
  size_t off = 5 * PL;
  float* kvT = (float*)(ws + off); off += (size_t)192 * 4096 * 4;
  float* ksum = (float*)(ws + off); off += (size_t)192 * 64 * 4;
  unsigned short* qkvWt = (unsigned short*)(ws + off); off += (size_t)2304 * 768 * 2;
  unsigned short* projWt = (unsigned short*)(ws + off); off += (size_t)768 * 768 * 2;
  unsigned short* fc1Wt = (unsigned short*)(ws + off); off += (size_t)3072 * 768 * 2;
  unsigned short* fc2Wt = (unsigned short*)(ws + off); off += (size_t)768 * 3072 * 2;

  // 1. weight transpose+cast
  wt_kernel<<<dim3(72, 24), 256, 0, stream>>>(qkv_w, qkvWt, 768, 2304);
  wt_kernel<<<dim3(24, 24), 256, 0, stream>>>(proj_w, projWt, 768, 768);
  wt_kernel<<<dim3(96, 24), 256, 0, stream>>>(fc1_w, fc1Wt, 768, 3072);
  wt_kernel<<<dim3(24, 96), 256, 0, stream>>>(fc2_w, fc2Wt, 3072, 768);
  // 2. LN1
  ln_kernel<<<16384, 256, 0, stream>>>(x, ln1_w, ln1_b, xn);
  // 3. qkv GEMM with elu+1 + transposed k/v scatter
  gemm256_k<2><<<dim3(9, 256), 512, 0, stream>>>(xn, qkvWt, qkv_b, 2304, 768, q, kT, vT, nullptr);
  // 4. ksum
  ksum_kernel<<<192, 256, 0, stream>>>(kT, ksum);
  // 5. kv
  kv_kernel<<<192, 256, 0, stream>>>(kT, vT, kvT);
  // 6. attention out
  attn_out_kernel<<<768, 256, 0, stream>>>(q, kvT, ksum, attnout);
  // 7. proj GEMM -> y
  gemm256_k<0><<<dim3(3, 256), 512, 0, stream>>>(attnout, projWt, proj_b, 768, 768, ybuf, nullptr,
                                                 nullptr, nullptr);
  // 8. residual + LN2 (x2 lives in d_out)
  fuse_kernel<<<16384, 256, 0, stream>>>(x, ybuf, ln2_w, ln2_b, out, xn2);
  // 9. fc1 + gelu
  gemm256_k<1><<<dim3(12, 256), 512, 0, stream>>>(xn2, fc1Wt, fc1_b, 3072, 768, hbuf, nullptr,
                                                  nullptr, nullptr);
  // 10. fc2 + residual RMW into out
  gemm256_k<3><<<dim3(3, 256), 512, 0, stream>>>(hbuf, fc2Wt, fc2_b, 768, 3072, nullptr, nullptr,
                                                 nullptr, out);
  (void)in_sizes; (void)n_in; (void)out_size; (void)ws_size;
}

// Round 3
// 1636.622 us; speedup vs baseline: 1.2123x; 1.0595x over previous
//
#include <hip/hip_runtime.h>

#define DEVI __device__ __forceinline__

typedef __attribute__((ext_vector_type(8))) short bf16x8;
typedef __attribute__((ext_vector_type(4))) float f32x4;
typedef __attribute__((ext_vector_type(4))) unsigned short usx4;

DEVI float bf2f(unsigned short u) {
  unsigned int b = ((unsigned int)u) << 16;
  float f;
  __builtin_memcpy(&f, &b, 4);
  return f;
}
DEVI unsigned short f2bf(float f) {
  unsigned int x;
  __builtin_memcpy(&x, &f, 4);
  x += 0x7FFFu + ((x >> 16) & 1u);
  return (unsigned short)(x >> 16);
}
DEVI void gload_lds16(const void* g, void* l) {
  __builtin_amdgcn_global_load_lds((const __attribute__((address_space(1))) void*)g,
                                   (__attribute__((address_space(3))) void*)l,
                                   16, 0, 0);
}

// ---------------------------------------------------------------------------
// Weight transpose + cast: W[K][N] fp32 -> Wt[N][K] bf16
// ---------------------------------------------------------------------------
__global__ __launch_bounds__(256) void wt_kernel(const float* __restrict__ W,
                                                 unsigned short* __restrict__ Wt,
                                                 int K, int N) {
  __shared__ float t[32][33];
  const int tx = threadIdx.x & 31, ty = threadIdx.x >> 5;  // 32 x 8
  const int n0 = blockIdx.x * 32, k0 = blockIdx.y * 32;
#pragma unroll
  for (int i = 0; i < 4; ++i)
    t[ty * 4 + i][tx] = W[(size_t)(k0 + ty * 4 + i) * N + n0 + tx];
  __syncthreads();
#pragma unroll
  for (int i = 0; i < 4; ++i)
    Wt[(size_t)(n0 + ty * 4 + i) * K + k0 + tx] = f2bf(t[tx][ty * 4 + i]);
}

// ---------------------------------------------------------------------------
// LayerNorm: x fp32 [rows][768] -> bf16 out. One wave per row.
// ---------------------------------------------------------------------------
__global__ __launch_bounds__(256) void ln_kernel(const float* __restrict__ x,
                                                 const float* __restrict__ w,
                                                 const float* __restrict__ b,
                                                 unsigned short* __restrict__ o) {
  const int lane = threadIdx.x & 63;
  const int wave = threadIdx.x >> 6;
  const size_t row = (size_t)blockIdx.x * 4 + wave;
  const float* xr = x + row * 768;
  float v[12];
  float s = 0.f, sq = 0.f;
#pragma unroll
  for (int i = 0; i < 3; ++i) {
    const float4 f = *(const float4*)&xr[i * 256 + lane * 4];
    v[i * 4 + 0] = f.x; v[i * 4 + 1] = f.y; v[i * 4 + 2] = f.z; v[i * 4 + 3] = f.w;
    s += f.x + f.y + f.z + f.w;
    sq += f.x * f.x + f.y * f.y + f.z * f.z + f.w * f.w;
  }
#pragma unroll
  for (int off = 32; off > 0; off >>= 1) {
    s += __shfl_xor(s, off);
    sq += __shfl_xor(sq, off);
  }
  const float mu = s * (1.f / 768.f);
  const float rs = rsqrtf(sq * (1.f / 768.f) - mu * mu + 1e-8f);
  unsigned short* orow = o + row * 768;
#pragma unroll
  for (int i = 0; i < 3; ++i) {
    usx4 st;
#pragma unroll
    for (int j = 0; j < 4; ++j) {
      const int c = i * 256 + lane * 4 + j;
      st[j] = f2bf((v[i * 4 + j] - mu) * rs * w[c] + b[c]);
    }
    *(usx4*)&orow[i * 256 + lane * 4] = st;
  }
}

// ---------------------------------------------------------------------------
// Fused residual + LayerNorm: x2 = x + y (y bf16); write x2 fp32 and LN(x2) bf16
// ---------------------------------------------------------------------------
__global__ __launch_bounds__(256) void fuse_kernel(const float* __restrict__ x,
                                                   const unsigned short* __restrict__ y,
                                                   const float* __restrict__ w,
                                                   const float* __restrict__ b,
                                                   float* __restrict__ x2,
                                                   unsigned short* __restrict__ o) {
  const int lane = threadIdx.x & 63;
  const int wave = threadIdx.x >> 6;
  const size_t row = (size_t)blockIdx.x * 4 + wave;
  const float* xr = x + row * 768;
  const unsigned short* yr = y + row * 768;
  float* x2r = x2 + row * 768;
  float v[12];
  float s = 0.f, sq = 0.f;
#pragma unroll
  for (int i = 0; i < 3; ++i) {
    const float4 f = *(const float4*)&xr[i * 256 + lane * 4];
    const usx4 yv = *(const usx4*)&yr[i * 256 + lane * 4];
    float t0 = f.x + bf2f(yv[0]);
    float t1 = f.y + bf2f(yv[1]);
    float t2 = f.z + bf2f(yv[2]);
    float t3 = f.w + bf2f(yv[3]);
    v[i * 4 + 0] = t0; v[i * 4 + 1] = t1; v[i * 4 + 2] = t2; v[i * 4 + 3] = t3;
    s += t0 + t1 + t2 + t3;
    sq += t0 * t0 + t1 * t1 + t2 * t2 + t3 * t3;
    float4 fo; fo.x = t0; fo.y = t1; fo.z = t2; fo.w = t3;
    *(float4*)&x2r[i * 256 + lane * 4] = fo;
  }
#pragma unroll
  for (int off = 32; off > 0; off >>= 1) {
    s += __shfl_xor(s, off);
    sq += __shfl_xor(sq, off);
  }
  const float mu = s * (1.f / 768.f);
  const float rs = rsqrtf(sq * (1.f / 768.f) - mu * mu + 1e-8f);
  unsigned short* orow = o + row * 768;
#pragma unroll
  for (int i = 0; i < 3; ++i) {
    usx4 st;
#pragma unroll
    for (int j = 0; j < 4; ++j) {
      const int c = i * 256 + lane * 4 + j;
      st[j] = f2bf((v[i * 4 + j] - mu) * rs * w[c] + b[c]);
    }
    *(usx4*)&orow[i * 256 + lane * 4] = st;
  }
}

// ---------------------------------------------------------------------------
// 256x256 bf16 MFMA GEMM engine. BK=32, 512 threads (8 waves, 2Mx4N),
// 4-buffer LDS ring (128KB). Two barrier-delimited phases per K-tile
// (T3+T4+T5): each phase {ds_read subtile + 2 gloads -> lgkmcnt(0) ->
// barrier -> setprio MFMA cluster}. Counted vmcnt(8) once per tile.
// XOR chunk swizzle staged via pre-swizzled global source.
// C = A[M,K] @ Bt[N,K]^T + bias. Epilogues 0..3.
// ---------------------------------------------------------------------------
template <int EPI>
__global__ __launch_bounds__(512, 2) void gemm256_k(
    const unsigned short* __restrict__ A, const unsigned short* __restrict__ Bt,
    const float* __restrict__ bias, int N, int K,
    unsigned short* __restrict__ O0, unsigned short* __restrict__ O1,
    unsigned short* __restrict__ O2, float* __restrict__ OF) {
  __shared__ char lds[131072];
  const int tid = threadIdx.x;
  const int lane = tid & 63, wave = tid >> 6;
  const int wr = wave >> 2, wc = wave & 3;

  // T1: XCD-chunked block swizzle (nwg % 8 == 0 for all our grids)
  const int gx = gridDim.x;
  const int nwg = gx * gridDim.y;
  const int cpx = nwg >> 3;
  const int wgid = blockIdx.x + gx * blockIdx.y;
  const int v = (wgid & 7) * cpx + (wgid >> 3);
  const size_t n0 = (size_t)(v % gx) * 256;
  const size_t m0 = (size_t)(v / gx) * 256;

  const size_t ldg = (size_t)K * 2;  // row stride bytes for A and Bt
  const char* Abase = (const char*)A + m0 * ldg;
  const char* Bbase = (const char*)Bt + n0 * ldg;

  // staging: phys chunk q in [0,1024) holds logical (row = rp*2 + (lc>>2),
  // kchunk = lc&3) with rp=q>>3, lc=(q&7)^(rp&7). Source pre-swizzled.
  const int q0 = tid, q1 = tid + 512;
  const int rp0 = q0 >> 3, rp1 = q1 >> 3;
  const int lc0 = (q0 & 7) ^ (rp0 & 7), lc1 = (q1 & 7) ^ (rp1 & 7);
  const size_t go0 = (size_t)(rp0 * 2 + (lc0 >> 2)) * ldg + (size_t)(lc0 & 3) * 16;
  const size_t go1 = (size_t)(rp1 * 2 + (lc1 >> 2)) * ldg + (size_t)(lc1 & 3) * 16;
  const char* aS0 = Abase + go0;
  const char* aS1 = Abase + go1;
  const char* bS0 = Bbase + go0;
  const char* bS1 = Bbase + go1;
  char* ldsb = (char*)lds;
  const int d0 = tid * 16, d1 = 8192 + tid * 16;

  f32x4 acc[8][4];
#pragma unroll
  for (int m = 0; m < 8; ++m)
#pragma unroll
    for (int n = 0; n < 4; ++n) acc[m][n] = f32x4{0.f, 0.f, 0.f, 0.f};

  // fragment-read addressing (swizzled)
  const int L = lane & 15;
  const int kc4 = lane >> 4;
  const int pcv = (((L & 1) << 2) | kc4) ^ (L >> 1);
  const int aro = wr * 8192 + (L >> 1) * 128 + pcv * 16;
  const int bro = 16384 + wc * 4096 + (L >> 1) * 128 + pcv * 16;

  const int nt = K >> 5;

#define STAGE_A(tt)                                            \
  do {                                                         \
    char* dst_ = ldsb + ((tt) & 3) * 32768;                    \
    const size_t ko_ = (size_t)(tt) * 64;                      \
    gload_lds16(aS0 + ko_, dst_ + d0);                         \
    gload_lds16(aS1 + ko_, dst_ + d1);                         \
  } while (0)
#define STAGE_B(tt)                                            \
  do {                                                         \
    char* dst_ = ldsb + ((tt) & 3) * 32768;                    \
    const size_t ko_ = (size_t)(tt) * 64;                      \
    gload_lds16(bS0 + ko_, dst_ + 16384 + d0);                 \
    gload_lds16(bS1 + ko_, dst_ + 16384 + d1);                 \
  } while (0)

  STAGE_A(0); STAGE_B(0);
  STAGE_A(1); STAGE_B(1);
  STAGE_A(2); STAGE_B(2);
  // prologue: buffer 0 must be resident before first reads
  asm volatile("s_waitcnt vmcnt(8)" ::: "memory");
  __builtin_amdgcn_s_barrier();

  for (int t = 0; t < nt; ++t) {
    const char* base = ldsb + (t & 3) * 32768;
    // ---- window A: read bF + aF[0..3], issue A-half of stage t+3 ----
    bf16x8 bF[4], aF0[4];
#pragma unroll
    for (int n = 0; n < 4; ++n) bF[n] = *(const bf16x8*)(base + bro + n * 1024);
#pragma unroll
    for (int m = 0; m < 4; ++m) aF0[m] = *(const bf16x8*)(base + aro + m * 1024);
    if (t + 3 < nt) STAGE_A(t + 3);
    asm volatile("s_waitcnt lgkmcnt(0)" ::: "memory");
    __builtin_amdgcn_s_barrier();
    __builtin_amdgcn_sched_barrier(0);
    __builtin_amdgcn_s_setprio(1);
#pragma unroll
    for (int m = 0; m < 4; ++m)
#pragma unroll
      for (int n = 0; n < 4; ++n)
        acc[m][n] = __builtin_amdgcn_mfma_f32_16x16x32_bf16(aF0[m], bF[n], acc[m][n], 0, 0, 0);
    __builtin_amdgcn_s_setprio(0);
    __builtin_amdgcn_sched_barrier(0);
    // ---- window B: read aF[4..7], issue B-half of stage t+3 ----
    bf16x8 aF1[4];
#pragma unroll
    for (int m = 0; m < 4; ++m) aF1[m] = *(const bf16x8*)(base + aro + (m + 4) * 1024);
    if (t + 3 < nt) STAGE_B(t + 3);
    {
      const int rem = nt - t;
      if (rem >= 4)
        asm volatile("s_waitcnt vmcnt(8) lgkmcnt(0)" ::: "memory");
      else if (rem == 3)
        asm volatile("s_waitcnt vmcnt(4) lgkmcnt(0)" ::: "memory");
      else
        asm volatile("s_waitcnt vmcnt(0) lgkmcnt(0)" ::: "memory");
    }
    __builtin_amdgcn_s_barrier();
    __builtin_amdgcn_sched_barrier(0);
    __builtin_amdgcn_s_setprio(1);
#pragma unroll
    for (int m = 0; m < 4; ++m)
#pragma unroll
      for (int n = 0; n < 4; ++n)
        acc[m + 4][n] = __builtin_amdgcn_mfma_f32_16x16x32_bf16(aF1[m], bF[n], acc[m + 4][n], 0, 0, 0);
    __builtin_amdgcn_s_setprio(0);
    __builtin_amdgcn_sched_barrier(0);
  }
#undef STAGE_A
#undef STAGE_B

  const int rl = (lane >> 4) * 4;
  const int cl = lane & 15;

  if (EPI == 2) {
    // qkv epilogue. Wave's 128x64 region maps to exactly one (t,h) section.
    const int cbase = (int)n0 + wc * 64;       // multiple of 64
    const int tsec = cbase / 768;
    const int h = (cbase - tsec * 768) >> 6;
    const int rbase = (int)m0 + wr * 128;      // within one b (4096 % 256 == 0)
    const int b = rbase >> 12;
    const int s0w = rbase & 4095;
    const size_t bh = (size_t)b * 12 + h;
    if (tsec == 0) {
      // q[bh][s][d], elu+1, direct store
#pragma unroll
      for (int m = 0; m < 8; ++m)
#pragma unroll
        for (int n = 0; n < 4; ++n) {
          const int d = n * 16 + cl;
          const float bv = bias[cbase + d];
#pragma unroll
          for (int j = 0; j < 4; ++j) {
            float val = acc[m][n][j] + bv;
            val = val > 0.f ? val + 1.f : __expf(val);
            O0[(bh * 4096 + (size_t)(s0w + m * 16 + rl + j)) * 64 + d] = f2bf(val);
          }
        }
    } else {
      // k (elu+1) or v -> transpose via private 16KB LDS slice -> [bh][d][s]
      unsigned short* dst = (tsec == 1) ? O1 : O2;
      char* wlds = ldsb + wave * 16384;  // [c2:64][r2:128] bf16, XOR-swizzled
#pragma unroll
      for (int m = 0; m < 8; ++m)
#pragma unroll
        for (int n = 0; n < 4; ++n) {
          const int c2 = n * 16 + cl;
          const float bv = bias[cbase + c2];
          usx4 st;
#pragma unroll
          for (int j = 0; j < 4; ++j) {
            float val = acc[m][n][j] + bv;
            if (tsec == 1) val = val > 0.f ? val + 1.f : __expf(val);
            st[j] = f2bf(val);
          }
          const int r2 = m * 16 + rl;
          *(usx4*)(wlds + c2 * 256 + ((r2 * 2) ^ ((c2 & 7) << 5))) = st;
        }
      asm volatile("s_waitcnt lgkmcnt(0)" ::: "memory");
#pragma unroll 4
      for (int dl = 0; dl < 64; ++dl) {
        const unsigned int pr =
            *(const unsigned int*)(wlds + dl * 256 + ((lane * 4) ^ ((dl & 7) << 5)));
        *(unsigned int*)&dst[(bh * 64 + dl) * 4096 + (size_t)(s0w + lane * 2)] = pr;
      }
    }
    return;
  }

  // common epilogue (EPI 0, 1, 3)
#pragma unroll
  for (int m = 0; m < 8; ++m) {
    const size_t r0 = m0 + wr * 128 + m * 16 + rl;
#pragma unroll
    for (int n = 0; n < 4; ++n) {
      const size_t c = n0 + wc * 64 + n * 16 + cl;
      const float bv = bias[c];
      if (EPI == 0) {
#pragma unroll
        for (int j = 0; j < 4; ++j) O0[(r0 + j) * (size_t)N + c] = f2bf(acc[m][n][j] + bv);
      } else if (EPI == 1) {
#pragma unroll
        for (int j = 0; j < 4; ++j) {
          float val = acc[m][n][j] + bv;
          val = 0.5f * val * (1.0f + erff(val * 0.70710678118654752f));
          O0[(r0 + j) * (size_t)N + c] = f2bf(val);
        }
      } else {  // EPI == 3: residual RMW into fp32 out
#pragma unroll
        for (int j = 0; j < 4; ++j) {
          const size_t idx = (r0 + j) * (size_t)N + c;
          OF[idx] += acc[m][n][j] + bv;
        }
      }
    }
  }
}

// ---------------------------------------------------------------------------
// kv[d][e] = sum_s k[s,d] v[s,e] per (b,h). kT/vT are [bh][64][4096] bf16.
// Writes kvT[bh][e][d] fp32. 4 waves split s-range; LDS reduce.
// ---------------------------------------------------------------------------
__global__ __launch_bounds__(256) void kv_kernel(const unsigned short* __restrict__ kT,
                                                 const unsigned short* __restrict__ vT,
                                                 float* __restrict__ kvT) {
  __shared__ float red[4 * 64 * 64];  // 64 KB
  const int tid = threadIdx.x;
  const int lane = tid & 63, wave = tid >> 6;
  const size_t bh = blockIdx.x;
  const unsigned short* kb = kT + bh * (size_t)(64 * 4096);
  const unsigned short* vb = vT + bh * (size_t)(64 * 4096);
  f32x4 acc[4][4];
#pragma unroll
  for (int m = 0; m < 4; ++m)
#pragma unroll
    for (int n = 0; n < 4; ++n) acc[m][n] = f32x4{0.f, 0.f, 0.f, 0.f};
  const int kh = (lane >> 4) * 8;
  for (int st = 0; st < 32; ++st) {
    const int s0 = wave * 1024 + st * 32 + kh;
    bf16x8 aF[4], bF[4];
#pragma unroll
    for (int m = 0; m < 4; ++m)
      aF[m] = *(const bf16x8*)&kb[(size_t)((lane & 15) + 16 * m) * 4096 + s0];
#pragma unroll
    for (int n = 0; n < 4; ++n)
      bF[n] = *(const bf16x8*)&vb[(size_t)((lane & 15) + 16 * n) * 4096 + s0];
#pragma unroll
    for (int m = 0; m < 4; ++m)
#pragma unroll
      for (int n = 0; n < 4; ++n)
        acc[m][n] = __builtin_amdgcn_mfma_f32_16x16x32_bf16(aF[m], bF[n], acc[m][n], 0, 0, 0);
  }
#pragma unroll
  for (int m = 0; m < 4; ++m)
#pragma unroll
    for (int n = 0; n < 4; ++n)
#pragma unroll
      for (int j = 0; j < 4; ++j)
        red[wave * 4096 + (m * 16 + (lane >> 4) * 4 + j) * 64 + n * 16 + (lane & 15)] =
            acc[m][n][j];
  __syncthreads();
  for (int i = 0; i < 16; ++i) {
    const int f = i * 256 + tid;
    float s = 0.f;
#pragma unroll
    for (int w = 0; w < 4; ++w) s += red[w * 4096 + f];
    const int d = f >> 6, e = f & 63;
    kvT[bh * 4096 + e * 64 + d] = s;  // transposed store
  }
}

// ---------------------------------------------------------------------------
// ksum[bh][d] = sum_s kT[bh][d][s]
// ---------------------------------------------------------------------------
__global__ __launch_bounds__(256) void ksum_kernel(const unsigned short* __restrict__ kT,
                                                   float* __restrict__ ksum) {
  __shared__ float part[256];
  const int tid = threadIdx.x;
  const int d = tid & 63, p = tid >> 6;
  const size_t bh = blockIdx.x;
  const unsigned short* kb = kT + bh * (size_t)(64 * 4096) + (size_t)d * 4096 + p * 1024;
  float s = 0.f;
  for (int i = 0; i < 128; ++i) {
    const bf16x8 v = *(const bf16x8*)&kb[i * 8];
#pragma unroll
    for (int j = 0; j < 8; ++j) s += bf2f((unsigned short)v[j]);
  }
  part[tid] = s;
  __syncthreads();
  if (tid < 64) ksum[bh * 64 + d] = part[d] + part[64 + d] + part[128 + d] + part[192 + d];
}

// ---------------------------------------------------------------------------
// attn out: out[s,e] = z_s * sum_d q[s,d] kv[d,e]; z_s = 1/sum_d q[s,d] ksum[d]
// ---------------------------------------------------------------------------
__global__ __launch_bounds__(256) void attn_out_kernel(const unsigned short* __restrict__ q,
                                                       const float* __restrict__ kvT,
                                                       const float* __restrict__ ksum,
                                                       unsigned short* __restrict__ attnout) {
  __shared__ float kvl[4096];
  __shared__ float ksl[64];
  __shared__ float zl[4 * 64];
  const int tid = threadIdx.x;
  const int lane = tid & 63, wave = tid >> 6;
  const int bh = blockIdx.x >> 2;
  const int chunk = blockIdx.x & 3;
  const int b = bh / 12, h = bh % 12;
  const float* kvb = kvT + (size_t)bh * 4096;
  for (int i = tid; i < 4096; i += 256) kvl[i] = kvb[i];
  if (tid < 64) ksl[tid] = ksum[(size_t)bh * 64 + tid];
  __syncthreads();

  const int kh = (lane >> 4) * 8;
  bf16x8 bF[4], ksF;
#pragma unroll
  for (int n = 0; n < 4; ++n) {
    bf16x8 t;
#pragma unroll
    for (int j = 0; j < 8; ++j)
      t[j] = (short)f2bf(kvl[((lane & 15) + 16 * n) * 64 + kh + j]);
    bF[n] = t;
  }
  {
    bf16x8 t;
#pragma unroll
    for (int j = 0; j < 8; ++j)
      t[j] = ((lane & 15) == 0) ? (short)f2bf(ksl[kh + j]) : (short)0;
    ksF = t;
  }
  const unsigned short* qb = q + (size_t)bh * 4096 * 64;

  for (int st = 0; st < 4; ++st) {
    const int s0 = chunk * 1024 + wave * 256 + st * 64;
    bf16x8 aF[4];
#pragma unroll
    for (int m = 0; m < 4; ++m)
      aF[m] = *(const bf16x8*)&qb[(size_t)(s0 + (lane & 15) + 16 * m) * 64 + kh];
    f32x4 acc[4][4];
    f32x4 dacc[4];
#pragma unroll
    for (int m = 0; m < 4; ++m) {
      dacc[m] = f32x4{0.f, 0.f, 0.f, 0.f};
#pragma unroll
      for (int n = 0; n < 4; ++n) acc[m][n] = f32x4{0.f, 0.f, 0.f, 0.f};
    }
#pragma unroll
    for (int m = 0; m < 4; ++m) {
#pragma unroll
      for (int n = 0; n < 4; ++n)
        acc[m][n] = __builtin_amdgcn_mfma_f32_16x16x32_bf16(aF[m], bF[n], acc[m][n], 0, 0, 0);
      dacc[m] = __builtin_amdgcn_mfma_f32_16x16x32_bf16(aF[m], ksF, dacc[m], 0, 0, 0);
    }
    if ((lane & 15) == 0) {
#pragma unroll
      for (int m = 0; m < 4; ++m)
#pragma unroll
        for (int j = 0; j < 4; ++j)
          zl[wave * 64 + m * 16 + (lane >> 4) * 4 + j] = 1.0f / dacc[m][j];
    }
    __syncthreads();
#pragma unroll
    for (int m = 0; m < 4; ++m)
#pragma unroll
      for (int n = 0; n < 4; ++n)
#pragma unroll
        for (int j = 0; j < 4; ++j) {
          const int sl = m * 16 + (lane >> 4) * 4 + j;
          const int s = s0 + sl;
          const float val = acc[m][n][j] * zl[wave * 64 + sl];
          const int e = n * 16 + (lane & 15);
          attnout[((size_t)b * 4096 + s) * 768 + h * 64 + e] = f2bf(val);
        }
    __syncthreads();
  }
}

// ---------------------------------------------------------------------------
extern "C" void kernel_launch(void* const* d_in, const int* in_sizes, int n_in,
                              void* d_out, int out_size, void* d_ws, size_t ws_size,
                              hipStream_t stream) {
  const float* x = (const float*)d_in[0];
  const float* qkv_w = (const float*)d_in[1];
  const float* qkv_b = (const float*)d_in[2];
  const float* proj_w = (const float*)d_in[3];
  const float* proj_b = (const float*)d_in[4];
  const float* fc1_w = (const float*)d_in[5];
  const float* fc1_b = (const float*)d_in[6];
  const float* fc2_w = (const float*)d_in[7];
  const float* fc2_b = (const float*)d_in[8];
  const float* ln1_w = (const float*)d_in[9];
  const float* ln1_b = (const float*)d_in[10];
  const float* ln2_w = (const float*)d_in[11];
  const float* ln2_b = (const float*)d_in[12];
  float* out = (float*)d_out;

  char* ws = (char*)d_ws;
  const size_t PL = (size_t)65536 * 768 * 2;  // one bf16 plane
  unsigned short* xn = (unsigned short*)(ws + 0 * PL);
  unsigned short* q = (unsigned short*)(ws + 1 * PL);
  unsigned short* kT = (unsigned short*)(ws + 2 * PL);
  unsigned short* vT = (unsigned short*)(ws + 3 * PL);
  unsigned short* attnout = xn;
  unsigned short* ybuf = kT;
  unsigned short* xn2 = (unsigned short*)(ws + 4 * PL);
  unsigned short* hbuf = (unsigned short*)(ws + 0 * PL);  // planes 0-3
  size_t off = 5 * PL;
  float* kvT = (float*)(ws + off); off += (size_t)192 * 4096 * 4;
  float* ksum = (float*)(ws + off); off += (size_t)192 * 64 * 4;
  unsigned short* qkvWt = (unsigned short*)(ws + off); off += (size_t)2304 * 768 * 2;
  unsigned short* projWt = (unsigned short*)(ws + off); off += (size_t)768 * 768 * 2;
  unsigned short* fc1Wt = (unsigned short*)(ws + off); off += (size_t)3072 * 768 * 2;
  unsigned short* fc2Wt = (unsigned short*)(ws + off); off += (size_t)768 * 3072 * 2;

  // 1. weight transpose+cast
  wt_kernel<<<dim3(72, 24), 256, 0, stream>>>(qkv_w, qkvWt, 768, 2304);
  wt_kernel<<<dim3(24, 24), 256, 0, stream>>>(proj_w, projWt, 768, 768);
  wt_kernel<<<dim3(96, 24), 256, 0, stream>>>(fc1_w, fc1Wt, 768, 3072);
  wt_kernel<<<dim3(24, 96), 256, 0, stream>>>(fc2_w, fc2Wt, 3072, 768);
  // 2. LN1
  ln_kernel<<<16384, 256, 0, stream>>>(x, ln1_w, ln1_b, xn);
  // 3. qkv GEMM with elu+1 + transposed k/v (LDS-transposed, coalesced)
  gemm256_k<2><<<dim3(9, 256), 512, 0, stream>>>(xn, qkvWt, qkv_b, 2304, 768, q, kT, vT, nullptr);
  // 4. ksum
  ksum_kernel<<<192, 256, 0, stream>>>(kT, ksum);
  // 5. kv
  kv_kernel<<<192, 256, 0, stream>>>(kT, vT, kvT);
  // 6. attention out
  attn_out_kernel<<<768, 256, 0, stream>>>(q, kvT, ksum, attnout);
  // 7. proj GEMM -> y
  gemm256_k<0><<<dim3(3, 256), 512, 0, stream>>>(attnout, projWt, proj_b, 768, 768, ybuf, nullptr,
                                                 nullptr, nullptr);
  // 8. residual + LN2 (x2 lives in d_out)
  fuse_kernel<<<16384, 256, 0, stream>>>(x, ybuf, ln2_w, ln2_b, out, xn2);
  // 9. fc1 + gelu
  gemm256_k<1><<<dim3(12, 256), 512, 0, stream>>>(xn2, fc1Wt, fc1_b, 3072, 768, hbuf, nullptr,
                                                  nullptr, nullptr);
  // 10. fc2 + residual RMW into out
  gemm256_k<3><<<dim3(3, 256), 512, 0, stream>>>(hbuf, fc2Wt, fc2_b, 768, 3072, nullptr, nullptr,
                                                 nullptr, out);
  (void)in_sizes; (void)n_in; (void)out_size; (void)ws_size;
}